// Round 10
// baseline (64.859 us; speedup 1.0000x reference)
//
#include <hip/hip_runtime.h>

// B=16384, S=336, F=8, H=1.
// 16 chunks/seq, 21 outputs each, W=32 warmup -> 53 uniform steps/thread.
// Register-streamed: each thread issues its 53 input loads up-front (all in
// flight), computes as data arrives (per-use vmcnt waits) -> memory and
// compute fully overlapped, no x-LDS, no staging barriers.
// WG = 256 threads = 16 seqs x 16 chunks; 1024 WGs -> 16 waves/CU.
constexpr int S_   = 336;
constexpr int F_   = 8;
constexpr int B_   = 16384;
constexpr int SEQW = 16;              // seqs per WG
constexpr int NCH  = 16;              // chunks per seq
constexpr int THR  = 256;             // SEQW * NCH
constexpr int LCH  = 21;              // stored outputs per chunk
constexpr int WRM  = 32;              // warmup steps
constexpr int NSTEP= WRM + LCH;       // 53
constexpr int OSTR = 337;             // output-stage LDS row stride
constexpr int NLD  = SEQW * S_ / THR; // 21 coalesced output stores / thread
constexpr float L2E = 1.4426950408889634f;
constexpr float K2  = 2.0f * L2E;
constexpr float IK2 = 1.0f / K2;

__device__ __forceinline__ float exp2_hw(float x){ float r; asm("v_exp_f32 %0, %1" : "=v"(r) : "v"(x)); return r; }
__device__ __forceinline__ float rcp_hw (float x){ float r; asm("v_rcp_f32 %0, %1" : "=v"(r) : "v"(x)); return r; }

struct LW { float wxi,whi,bi, wxf,whf,bf, wxg,whg,bg, wxo,who,bo; };

// Pre-scaled weights: sigmoid gates by -log2e, g-gate by +2*log2e.
// cs = 2*log2e*c; i-gate folded to K2*sigmoid via rcp scaling.
__device__ __forceinline__ void cell(float xin, float& h, float& cs, const LW& w) {
    float pi = fmaf(xin, w.wxi, w.bi);
    float pf = fmaf(xin, w.wxf, w.bf);
    float pg = fmaf(xin, w.wxg, w.bg);
    float po = fmaf(xin, w.wxo, w.bo);
    float zi = fmaf(h, w.whi, pi);
    float zf = fmaf(h, w.whf, pf);
    float zg = fmaf(h, w.whg, pg);
    float zo = fmaf(h, w.who, po);
    float ip = rcp_hw(fmaf(exp2_hw(zi), IK2, IK2));           // K2*sigmoid(zi)
    float f  = rcp_hw(1.0f + exp2_hw(zf));                    // sigmoid(zf)
    float g  = fmaf(-2.0f, rcp_hw(1.0f + exp2_hw(zg)), 1.0f); // tanh(zg)
    float o  = rcp_hw(1.0f + exp2_hw(zo));                    // sigmoid(zo)
    cs = fmaf(f, cs, ip * g);
    float t  = fmaf(-2.0f, rcp_hw(1.0f + exp2_hw(cs)), 1.0f); // tanh(c)
    h = o * t;
}

__global__ __launch_bounds__(THR, 4) void lstm_stream_kernel(
    const float* __restrict__ x,
    const float* __restrict__ Wx1, const float* __restrict__ Wh1, const float* __restrict__ b1,
    const float* __restrict__ Wx2, const float* __restrict__ Wh2, const float* __restrict__ b2,
    const float* __restrict__ fcW, const float* __restrict__ fcb,
    float* __restrict__ out)
{
    __shared__ float xs[SEQW * OSTR];          // 21568 B (output staging)

    int t  = threadIdx.x;
    int wg = blockIdx.x;
    int c  = t >> 4;                           // chunk 0..15
    int s  = t & 15;                           // local seq

    // feature-7 column of this thread's sequence
    const float* gp = x + (size_t)(wg * SEQW + s) * (S_ * F_) + (F_ - 1);
    int st0 = c * LCH - WRM;                   // first step (may be < 0)

    // ---- issue ALL chunk inputs; keep every load in flight ----
    float raw[NSTEP];
    #pragma unroll
    for (int u = 0; u < NSTEP; ++u) {
        int st  = st0 + u;
        int stc = st < 0 ? 0 : st;             // clamp (safe addr; masked at use)
        raw[u] = gp[stc * F_];
    }
    __builtin_amdgcn_sched_barrier(0);

    // uniform weights (scalar loads) while the stream is in flight
    LW w1, w2;
    w1.wxi = -L2E*Wx1[0]; w1.whi = -L2E*Wh1[0]; w1.bi = -L2E*b1[0];
    w1.wxf = -L2E*Wx1[1]; w1.whf = -L2E*Wh1[1]; w1.bf = -L2E*b1[1];
    w1.wxg =  K2 *Wx1[2]; w1.whg =  K2 *Wh1[2]; w1.bg =  K2 *b1[2];
    w1.wxo = -L2E*Wx1[3]; w1.who = -L2E*Wh1[3]; w1.bo = -L2E*b1[3];
    w2.wxi = -L2E*Wx2[0]; w2.whi = -L2E*Wh2[0]; w2.bi = -L2E*b2[0];
    w2.wxf = -L2E*Wx2[1]; w2.whf = -L2E*Wh2[1]; w2.bf = -L2E*b2[1];
    w2.wxg =  K2 *Wx2[2]; w2.whg =  K2 *Wh2[2]; w2.bg =  K2 *b2[2];
    w2.wxo = -L2E*Wx2[3]; w2.who = -L2E*Wh2[3]; w2.bo = -L2E*b2[3];
    float fw = fcW[0], fb = fcb[0];
    __builtin_amdgcn_sched_barrier(0);

    // ---- 53 uniform steps, consuming the stream in order ----
    float h1 = 0.f, cs1 = 0.f, h2 = 0.f, cs2 = 0.f;
    float r[LCH];
    #pragma unroll
    for (int u = 0; u < NSTEP; ++u) {
        float xv = raw[u];
        if (u < WRM) xv = (st0 + u < 0) ? 0.f : xv;   // pre-sequence -> 0 (exact)
        cell(xv, h1, cs1, w1);
        cell(h1, h2, cs2, w2);
        if (u >= WRM) r[u - WRM] = fmaf(h2, fw, fb);
    }

    // ---- output: r[] -> LDS -> coalesced global stores ----
    #pragma unroll
    for (int j = 0; j < LCH; ++j)
        xs[s * OSTR + c * LCH + j] = r[j];
    __syncthreads();

    float* ob = out + (size_t)wg * (SEQW * S_);
    #pragma unroll
    for (int j = 0; j < NLD; ++j) {
        int q  = t + THR * j;                  // < 5376
        int sq = (q * 3121) >> 20;             // q / 336
        int st = q - sq * 336;
        ob[q] = xs[sq * OSTR + st];
    }
}

extern "C" void kernel_launch(void* const* d_in, const int* in_sizes, int n_in,
                              void* d_out, int out_size, void* d_ws, size_t ws_size,
                              hipStream_t stream) {
    const float* x   = (const float*)d_in[0];
    const float* Wx1 = (const float*)d_in[1];
    const float* Wh1 = (const float*)d_in[2];
    const float* b1  = (const float*)d_in[3];
    const float* Wx2 = (const float*)d_in[4];
    const float* Wh2 = (const float*)d_in[5];
    const float* b2  = (const float*)d_in[6];
    const float* fcW = (const float*)d_in[7];
    const float* fcb = (const float*)d_in[8];
    float* out = (float*)d_out;

    int nwg = B_ / SEQW;                      // 1024 WGs x 256 threads
    lstm_stream_kernel<<<nwg, THR, 0, stream>>>(
        x, Wx1, Wh1, b1, Wx2, Wh2, b2, fcW, fcb, out);
}

// Round 11
// 44.285 us; speedup vs baseline: 1.4646x; 1.4646x over previous
//
#include <hip/hip_runtime.h>

// B=16384, S=336, F=8, H=1.
// Wave-private pipeline: WG = 1 wave (64 thr) = 4 seqs x 16 chunks.
// Each wave stages its 4 seqs' feature-7 column into its OWN LDS (no
// cross-wave barrier -> no phase lock), then computes 53 uniform steps
// (W=32 warmup, 21 outputs). 4096 WGs = 16 waves/CU free-running: waves
// in stage overlap waves in compute on the same SIMD.
constexpr int S_   = 336;
constexpr int F_   = 8;
constexpr int B_   = 16384;
constexpr int SEQW = 4;               // seqs per wave
constexpr int THR  = 64;              // 1 wave
constexpr int LCH  = 21;              // stored outputs per chunk (16 chunks)
constexpr int WRM  = 32;              // warmup steps (zero-padded region)
constexpr int NSTEP= WRM + LCH;       // 53
constexpr int LSTR = 369;             // LDS row: 32 pad + 336 + 1
constexpr int NLD  = SEQW * S_ / THR; // 21 staging loads / lane
constexpr float L2E = 1.4426950408889634f;
constexpr float K2  = 2.0f * L2E;
constexpr float IK2 = 1.0f / K2;

__device__ __forceinline__ float exp2_hw(float x){ float r; asm("v_exp_f32 %0, %1" : "=v"(r) : "v"(x)); return r; }
__device__ __forceinline__ float rcp_hw (float x){ float r; asm("v_rcp_f32 %0, %1" : "=v"(r) : "v"(x)); return r; }

struct LW { float wxi,whi,bi, wxf,whf,bf, wxg,whg,bg, wxo,who,bo; };

// Pre-scaled weights: sigmoid gates by -log2e, g-gate by +2*log2e.
// cs = 2*log2e*c; i-gate folded to K2*sigmoid via rcp scaling.
__device__ __forceinline__ void cell(float xin, float& h, float& cs, const LW& w) {
    float pi = fmaf(xin, w.wxi, w.bi);
    float pf = fmaf(xin, w.wxf, w.bf);
    float pg = fmaf(xin, w.wxg, w.bg);
    float po = fmaf(xin, w.wxo, w.bo);
    float zi = fmaf(h, w.whi, pi);
    float zf = fmaf(h, w.whf, pf);
    float zg = fmaf(h, w.whg, pg);
    float zo = fmaf(h, w.who, po);
    float ip = rcp_hw(fmaf(exp2_hw(zi), IK2, IK2));           // K2*sigmoid(zi)
    float f  = rcp_hw(1.0f + exp2_hw(zf));                    // sigmoid(zf)
    float g  = fmaf(-2.0f, rcp_hw(1.0f + exp2_hw(zg)), 1.0f); // tanh(zg)
    float o  = rcp_hw(1.0f + exp2_hw(zo));                    // sigmoid(zo)
    cs = fmaf(f, cs, ip * g);
    float t  = fmaf(-2.0f, rcp_hw(1.0f + exp2_hw(cs)), 1.0f); // tanh(c)
    h = o * t;
}

__global__ __launch_bounds__(THR, 4) void lstm_wavep_kernel(
    const float* __restrict__ x,
    const float* __restrict__ Wx1, const float* __restrict__ Wh1, const float* __restrict__ b1,
    const float* __restrict__ Wx2, const float* __restrict__ Wh2, const float* __restrict__ b2,
    const float* __restrict__ fcW, const float* __restrict__ fcb,
    float* __restrict__ out)
{
    __shared__ float xs[SEQW * LSTR];          // 5904 B, wave-private

    int l  = threadIdx.x;
    int wg = blockIdx.x;

    // ---- stage this wave's 4 seqs' feature-7 column (loads pinned first) ----
    const char* xb = (const char*)x + (size_t)wg * (SEQW * S_ * F_ * 4);
    float v[NLD];
    #pragma unroll
    for (int j = 0; j < NLD; ++j)
        v[j] = *(const float*)(xb + (size_t)((l + THR * j) * 32 + 28));
    __builtin_amdgcn_sched_barrier(0);

    // zero warmup pad + uniform weights while loads are in flight
    #pragma unroll
    for (int j = 0; j < 2; ++j) {
        int idx = l + THR * j;                 // < 128 = SEQW*WRM
        xs[(idx >> 5) * LSTR + (idx & 31)] = 0.f;
    }
    LW w1, w2;
    w1.wxi = -L2E*Wx1[0]; w1.whi = -L2E*Wh1[0]; w1.bi = -L2E*b1[0];
    w1.wxf = -L2E*Wx1[1]; w1.whf = -L2E*Wh1[1]; w1.bf = -L2E*b1[1];
    w1.wxg =  K2 *Wx1[2]; w1.whg =  K2 *Wh1[2]; w1.bg =  K2 *b1[2];
    w1.wxo = -L2E*Wx1[3]; w1.who = -L2E*Wh1[3]; w1.bo = -L2E*b1[3];
    w2.wxi = -L2E*Wx2[0]; w2.whi = -L2E*Wh2[0]; w2.bi = -L2E*b2[0];
    w2.wxf = -L2E*Wx2[1]; w2.whf = -L2E*Wh2[1]; w2.bf = -L2E*b2[1];
    w2.wxg =  K2 *Wx2[2]; w2.whg =  K2 *Wh2[2]; w2.bg =  K2 *b2[2];
    w2.wxo = -L2E*Wx2[3]; w2.who = -L2E*Wh2[3]; w2.bo = -L2E*b2[3];
    float fw = fcW[0], fb = fcb[0];
    __builtin_amdgcn_sched_barrier(0);

    #pragma unroll
    for (int j = 0; j < NLD; ++j) {
        int k  = l + THR * j;                  // < 1344
        int sq = (k * 3121) >> 20;             // k / 336
        int st = k - sq * 336;
        xs[sq * LSTR + WRM + st] = v[j];
    }
    __syncthreads();                           // single-wave WG: just a waitcnt

    // ---- 53 uniform steps from wave-private LDS ----
    int s = l >> 4;                            // local seq 0..3
    int c = l & 15;                            // chunk 0..15
    const float* xr = xs + s * LSTR + c * LCH;

    float h1 = 0.f, cs1 = 0.f, h2 = 0.f, cs2 = 0.f;
    float r[LCH];
    #pragma unroll
    for (int u = 0; u < NSTEP; ++u) {
        cell(xr[u], h1, cs1, w1);
        cell(h1,    h2, cs2, w2);
        if (u >= WRM) r[u - WRM] = fmaf(h2, fw, fb);
    }

    // ---- output: r[] -> LDS (reuse) -> coalesced global stores ----
    __syncthreads();                           // reads done before overwrite
    #pragma unroll
    for (int j = 0; j < LCH; ++j)
        xs[s * S_ + c * LCH + j] = r[j];       // seq-major linear
    __syncthreads();

    float* ob = out + (size_t)wg * (SEQW * S_);
    #pragma unroll
    for (int j = 0; j < NLD; ++j) {
        int q = l + THR * j;                   // < 1344
        ob[q] = xs[q];
    }
}

extern "C" void kernel_launch(void* const* d_in, const int* in_sizes, int n_in,
                              void* d_out, int out_size, void* d_ws, size_t ws_size,
                              hipStream_t stream) {
    const float* x   = (const float*)d_in[0];
    const float* Wx1 = (const float*)d_in[1];
    const float* Wh1 = (const float*)d_in[2];
    const float* b1  = (const float*)d_in[3];
    const float* Wx2 = (const float*)d_in[4];
    const float* Wh2 = (const float*)d_in[5];
    const float* b2  = (const float*)d_in[6];
    const float* fcW = (const float*)d_in[7];
    const float* fcb = (const float*)d_in[8];
    float* out = (float*)d_out;

    int nwg = B_ / SEQW;                      // 4096 single-wave WGs
    lstm_wavep_kernel<<<nwg, THR, 0, stream>>>(
        x, Wx1, Wh1, b1, Wx2, Wh2, b2, fcW, fcb, out);
}